// Round 6
// baseline (6112.448 us; speedup 1.0000x reference)
//
#include <hip/hip_runtime.h>

// Neural ODE RK4 scan: 1024 independent batch rows, one block (4 waves) per row.
// Wave w owns hidden slice j in [64w, 64w+64). The 128 per-lane weight values
// (W1 column + W2 row slice) are loaded ONCE and pinned into VGPRs with
// asm "+v" ties; W1/W2 are NOT restrict-qualified so the in-loop memory
// clobbers make any in-loop reload illegal (defeats RA load-rematerialization,
// which caused round-3/4's 1.24 GB refetch at VGPR=84).
// LDS: wave-private x/activation broadcast buffers + stride-5 conflict-free
// cross-wave partial exchange; exactly 1 raw s_barrier per eval.

#define NB 1024
#define ND 64
#define NH 256

#define R16(M) M(0) M(1) M(2) M(3) M(4) M(5) M(6) M(7) \
               M(8) M(9) M(10) M(11) M(12) M(13) M(14) M(15)

// Pin a value into a VGPR: asm output is not rematerializable.
#define OPAQUE(x) asm volatile("" : "+v"(x))

__device__ __forceinline__ float fast_tanh(float x) {
    // tanh(x) = 1 - 2/(1+e^{2x})
    float e = __expf(2.0f * x);
    float r = __builtin_amdgcn_rcpf(e + 1.0f);
    return 1.0f - 2.0f * r;
}

// lgkmcnt(0) then barrier: part-write visible; no vmcnt drain (output stores
// from previous steps keep flowing).
#define BLOCK_SYNC() do {                                        \
    asm volatile("s_waitcnt lgkmcnt(0)" ::: "memory");           \
    __builtin_amdgcn_s_barrier();                                \
    asm volatile("" ::: "memory");                               \
} while (0)

// GEMM1 step q: h += W1col[4q..4q+3] * x[4q..4q+3] (uniform-addr LDS bcast)
#define G1(q) { float4 xv = xv4[q];                              \
    h0 = fmaf(W1x##q, xv.x, h0);                                 \
    h1 = fmaf(W1y##q, xv.y, h1);                                 \
    h0 = fmaf(W1z##q, xv.z, h0);                                 \
    h1 = fmaf(W1w##q, xv.w, h1); }

// GEMM2 step q: p += a[4q..4q+3] * W2row[4q..4q+3]
#define G2(q) { float4 av = av4[q];                              \
    p0 = fmaf(av.x, W2x##q, p0);                                 \
    p1 = fmaf(av.y, W2y##q, p1);                                 \
    p0 = fmaf(av.z, W2z##q, p0);                                 \
    p1 = fmaf(av.w, W2w##q, p1); }

// One func eval: KOUT = (tanh(XIN@W1+b1)@W2+b2)[l]; XIN/KOUT elem-per-lane,
// replicated across the 4 waves (each wave holds the full 64-vector; the
// FMAs themselves are not redundant - waves own disjoint hidden slices).
#define EVAL(XIN, KOUT) do {                                     \
    xbuf[w][l] = (XIN);                                          \
    float h0 = b1l, h1 = 0.0f;                                   \
    R16(G1)                                                      \
    float a = fast_tanh(h0 + h1);                                \
    abuf[w][l] = a;                                              \
    float p0 = 0.0f, p1 = 0.0f;                                  \
    R16(G2)                                                      \
    part[pb][l][w] = p0 + p1;                                    \
    BLOCK_SYNC();                                                \
    KOUT = ((part[pb][l][0] + part[pb][l][1]) +                  \
            (part[pb][l][2] + part[pb][l][3])) + b2l;            \
    pb ^= 1;  /* WAR separated by next eval's barrier */         \
} while (0)

#define DECLW(q) float W1x##q, W1y##q, W1z##q, W1w##q,           \
                       W2x##q, W2y##q, W2z##q, W2w##q;
#define LOADW(q)                                                 \
    W1x##q = W1[(4*q + 0) * NH + j];                             \
    W1y##q = W1[(4*q + 1) * NH + j];                             \
    W1z##q = W1[(4*q + 2) * NH + j];                             \
    W1w##q = W1[(4*q + 3) * NH + j];                             \
    W2x##q = W2[((w << 6) + 4*q + 0) * ND + l];                  \
    W2y##q = W2[((w << 6) + 4*q + 1) * ND + l];                  \
    W2z##q = W2[((w << 6) + 4*q + 2) * ND + l];                  \
    W2w##q = W2[((w << 6) + 4*q + 3) * ND + l];
#define PINW(q)                                                  \
    OPAQUE(W1x##q); OPAQUE(W1y##q); OPAQUE(W1z##q); OPAQUE(W1w##q); \
    OPAQUE(W2x##q); OPAQUE(W2y##q); OPAQUE(W2z##q); OPAQUE(W2w##q);

__global__ __launch_bounds__(256, 2)
void node_rk4_kernel(const float* __restrict__ y0,
                     const float* __restrict__ t,
                     const float* W1,      // no restrict: in-loop reload illegal
                     const float* b1,
                     const float* W2,      // no restrict
                     const float* b2,
                     float* __restrict__ out,
                     int nsteps)
{
    const int row = blockIdx.x;
    const int tid = threadIdx.x;
    const int w   = tid >> 6;        // wave -> hidden slice
    const int l   = tid & 63;        // lane -> dim index / hidden offset
    const int j   = (w << 6) + l;    // owned hidden unit

    __shared__ __align__(16) float xbuf[4][ND];   // wave-private input bcast
    __shared__ __align__(16) float abuf[4][ND];   // wave-private activation bcast
    __shared__ float part[2][ND][5];              // stride-5: conflict-free

    R16(DECLW)
    R16(LOADW)
    R16(PINW)
    const float b1l = b1[j];
    const float b2l = b2[l];

    const float4* xv4 = reinterpret_cast<const float4*>(&xbuf[w][0]);
    const float4* av4 = reinterpret_cast<const float4*>(&abuf[w][0]);

    float y = y0[row * ND + l];
    if (w == 0) out[row * ND + l] = y;   // step-0 output = y0

    int pb = 0;

    for (int s = 0; s < nsteps; ++s) {
        float h  = t[s + 1] - t[s];      // func is autonomous; only h matters
        float hh = 0.5f * h;
        float k1, k2, k3, k4;
        EVAL(y, k1);
        EVAL(fmaf(hh, k1, y), k2);
        EVAL(fmaf(hh, k2, y), k3);
        EVAL(fmaf(h,  k3, y), k4);
        y = fmaf(h * (1.0f / 6.0f), (k1 + k4) + 2.0f * (k2 + k3), y);
        if (w == 0)                      // waves hold identical y; store once
            out[(size_t)(s + 1) * (NB * ND) + row * ND + l] = y;
    }
}

extern "C" void kernel_launch(void* const* d_in, const int* in_sizes, int n_in,
                              void* d_out, int out_size, void* d_ws, size_t ws_size,
                              hipStream_t stream) {
    const float* y0 = (const float*)d_in[0];
    const float* t  = (const float*)d_in[1];
    const float* W1 = (const float*)d_in[2];
    const float* b1 = (const float*)d_in[3];
    const float* W2 = (const float*)d_in[4];
    const float* b2 = (const float*)d_in[5];
    float* out = (float*)d_out;
    int nsteps = in_sizes[1] - 1;
    hipLaunchKernelGGL(node_rk4_kernel, dim3(NB), dim3(256), 0, stream,
                       y0, t, W1, b1, W2, b2, out, nsteps);
}

// Round 7
// 5982.004 us; speedup vs baseline: 1.0218x; 1.0218x over previous
//
#include <hip/hip_runtime.h>

// Neural ODE RK4 scan: 1024 independent batch rows, one block (4 waves) per row.
// Wave w owns hidden slice j in [64w, 64w+64); 128 weight floats per lane.
// KEY FIX (r6): amdgpu_waves_per_eu(2,2) pins the allocator's occupancy target
// to 2 waves/EU -> ~256-VGPR budget. Previous rounds: RA targeted 6 waves/EU
// (84-VGPR budget) and spilled all weights to scratch, reloading 512 B/lane
// per eval (the 1.24 GB FETCH residue and the +400cy/eval VALU overhead).
// LDS: wave-private x/act broadcast buffers + stride-5 conflict-free part
// exchange; exactly 1 raw s_barrier per eval.

#define NB 1024
#define ND 64
#define NH 256

#define R16(M) M(0) M(1) M(2) M(3) M(4) M(5) M(6) M(7) \
               M(8) M(9) M(10) M(11) M(12) M(13) M(14) M(15)

// Pin a value into a VGPR: asm output is not rematerializable (belt&braces
// against load-sinking; spills prevented by the waves_per_eu cap instead).
#define OPAQUE(x) asm volatile("" : "+v"(x))

__device__ __forceinline__ float fast_tanh(float x) {
    // tanh(x) = 1 - 2/(1+e^{2x})
    float e = __expf(2.0f * x);
    float r = __builtin_amdgcn_rcpf(e + 1.0f);
    return 1.0f - 2.0f * r;
}

// lgkmcnt(0) then barrier: part-write visible; no vmcnt drain (output stores
// from previous steps keep flowing).
#define BLOCK_SYNC() do {                                        \
    asm volatile("s_waitcnt lgkmcnt(0)" ::: "memory");           \
    __builtin_amdgcn_s_barrier();                                \
    asm volatile("" ::: "memory");                               \
} while (0)

// GEMM1 step q: h += W1col[4q..4q+3] * x[4q..4q+3] (uniform-addr LDS bcast)
#define G1(q) { float4 xv = xv4[q];                              \
    h0 = fmaf(W1x##q, xv.x, h0);                                 \
    h1 = fmaf(W1y##q, xv.y, h1);                                 \
    h0 = fmaf(W1z##q, xv.z, h0);                                 \
    h1 = fmaf(W1w##q, xv.w, h1); }

// GEMM2 step q: p += a[4q..4q+3] * W2row[4q..4q+3]
#define G2(q) { float4 av = av4[q];                              \
    p0 = fmaf(av.x, W2x##q, p0);                                 \
    p1 = fmaf(av.y, W2y##q, p1);                                 \
    p0 = fmaf(av.z, W2z##q, p0);                                 \
    p1 = fmaf(av.w, W2w##q, p1); }

// One func eval: KOUT = (tanh(XIN@W1+b1)@W2+b2)[l]; XIN/KOUT elem-per-lane,
// replicated across the 4 waves (waves own disjoint hidden slices).
#define EVAL(XIN, KOUT) do {                                     \
    xbuf[w][l] = (XIN);                                          \
    float h0 = b1l, h1 = 0.0f;                                   \
    R16(G1)                                                      \
    float a = fast_tanh(h0 + h1);                                \
    abuf[w][l] = a;                                              \
    float p0 = 0.0f, p1 = 0.0f;                                  \
    R16(G2)                                                      \
    part[pb][l][w] = p0 + p1;                                    \
    BLOCK_SYNC();                                                \
    KOUT = ((part[pb][l][0] + part[pb][l][1]) +                  \
            (part[pb][l][2] + part[pb][l][3])) + b2l;            \
    pb ^= 1;  /* WAR separated by next eval's barrier */         \
} while (0)

#define DECLW(q) float W1x##q, W1y##q, W1z##q, W1w##q,           \
                       W2x##q, W2y##q, W2z##q, W2w##q;
#define LOADW(q)                                                 \
    W1x##q = W1[(4*q + 0) * NH + j];                             \
    W1y##q = W1[(4*q + 1) * NH + j];                             \
    W1z##q = W1[(4*q + 2) * NH + j];                             \
    W1w##q = W1[(4*q + 3) * NH + j];                             \
    W2x##q = W2[((w << 6) + 4*q + 0) * ND + l];                  \
    W2y##q = W2[((w << 6) + 4*q + 1) * ND + l];                  \
    W2z##q = W2[((w << 6) + 4*q + 2) * ND + l];                  \
    W2w##q = W2[((w << 6) + 4*q + 3) * ND + l];
#define PINW(q)                                                  \
    OPAQUE(W1x##q); OPAQUE(W1y##q); OPAQUE(W1z##q); OPAQUE(W1w##q); \
    OPAQUE(W2x##q); OPAQUE(W2y##q); OPAQUE(W2z##q); OPAQUE(W2w##q);

__global__ __launch_bounds__(256)
__attribute__((amdgpu_waves_per_eu(2, 2)))   // RA budget = 2 waves/EU -> ~256 VGPR
void node_rk4_kernel(const float* __restrict__ y0,
                     const float* __restrict__ t,
                     const float* W1,      // no restrict: in-loop reload illegal
                     const float* b1,
                     const float* W2,      // no restrict
                     const float* b2,
                     float* __restrict__ out,
                     int nsteps)
{
    const int row = blockIdx.x;
    const int tid = threadIdx.x;
    const int w   = tid >> 6;        // wave -> hidden slice
    const int l   = tid & 63;        // lane -> dim index / hidden offset
    const int j   = (w << 6) + l;    // owned hidden unit

    __shared__ __align__(16) float xbuf[4][ND];   // wave-private input bcast
    __shared__ __align__(16) float abuf[4][ND];   // wave-private activation bcast
    __shared__ float part[2][ND][5];              // stride-5: conflict-free

    R16(DECLW)
    R16(LOADW)
    R16(PINW)
    const float b1l = b1[j];
    const float b2l = b2[l];

    const float4* xv4 = reinterpret_cast<const float4*>(&xbuf[w][0]);
    const float4* av4 = reinterpret_cast<const float4*>(&abuf[w][0]);

    float y = y0[row * ND + l];
    if (w == 0) out[row * ND + l] = y;   // step-0 output = y0

    int pb = 0;

    for (int s = 0; s < nsteps; ++s) {
        float h  = t[s + 1] - t[s];      // func is autonomous; only h matters
        float hh = 0.5f * h;
        float k1, k2, k3, k4;
        EVAL(y, k1);
        EVAL(fmaf(hh, k1, y), k2);
        EVAL(fmaf(hh, k2, y), k3);
        EVAL(fmaf(h,  k3, y), k4);
        y = fmaf(h * (1.0f / 6.0f), (k1 + k4) + 2.0f * (k2 + k3), y);
        if (w == 0)                      // waves hold identical y; store once
            out[(size_t)(s + 1) * (NB * ND) + row * ND + l] = y;
    }
}

extern "C" void kernel_launch(void* const* d_in, const int* in_sizes, int n_in,
                              void* d_out, int out_size, void* d_ws, size_t ws_size,
                              hipStream_t stream) {
    const float* y0 = (const float*)d_in[0];
    const float* t  = (const float*)d_in[1];
    const float* W1 = (const float*)d_in[2];
    const float* b1 = (const float*)d_in[3];
    const float* W2 = (const float*)d_in[4];
    const float* b2 = (const float*)d_in[5];
    float* out = (float*)d_out;
    int nsteps = in_sizes[1] - 1;
    hipLaunchKernelGGL(node_rk4_kernel, dim3(NB), dim3(256), 0, stream,
                       y0, t, W1, b1, W2, b2, out, nsteps);
}